// Round 1
// 412.277 us; speedup vs baseline: 1.0065x; 1.0065x over previous
//
#include <hip/hip_runtime.h>

#define NV 8192
#define FIN 256
#define FOUT 128
#define NSPLIT 8
#define SPLITW 1024   // NV / NSPLIT

typedef __bf16 bf16_t;
typedef __attribute__((ext_vector_type(8))) __bf16 bf16x8;
typedef __attribute__((ext_vector_type(16))) float f32x16;

// ---------------------------------------------------------------------------
// Kernel 1: Wh = h @ W  (fp32, exact). Stores WhbT (bf16, transposed [F][N]),
// Wh1 = Wh @ a[:128], Wh2 = Wh @ a[128:].  (unchanged — ~10 us, not the lever)
// ---------------------------------------------------------------------------
__global__ __launch_bounds__(256) void wh_kernel(
    const float* __restrict__ h, const float* __restrict__ W,
    const float* __restrict__ a,
    bf16_t* __restrict__ WhbT, float* __restrict__ Wh1, float* __restrict__ Wh2)
{
  __shared__ float As[64][34];    // [k][i] transposed A tile
  __shared__ float Bs[64][128];   // [k][f]
  __shared__ float Cs[32][129];
  __shared__ float red1[32][16];
  __shared__ float red2[32][16];
  const int t  = threadIdx.x;
  const int i0 = blockIdx.x * 32;
  const int c  = t & 15;   // col group: cols c*8 .. c*8+7
  const int r  = t >> 4;   // row group: rows r*2, r*2+1
  float acc0[8], acc1[8];
  #pragma unroll
  for (int j = 0; j < 8; j++) { acc0[j] = 0.f; acc1[j] = 0.f; }

  for (int k0 = 0; k0 < FIN; k0 += 64) {
    { // stage A (32 rows x 64 k), transposed into LDS
      const int ia = t >> 3;          // 0..31
      const int ka = (t & 7) * 8;     // 0..56
      const float* src = h + (size_t)(i0 + ia) * FIN + k0 + ka;
      float4 v0 = *(const float4*)src;
      float4 v1 = *(const float4*)(src + 4);
      As[ka+0][ia]=v0.x; As[ka+1][ia]=v0.y; As[ka+2][ia]=v0.z; As[ka+3][ia]=v0.w;
      As[ka+4][ia]=v1.x; As[ka+5][ia]=v1.y; As[ka+6][ia]=v1.z; As[ka+7][ia]=v1.w;
    }
    { // stage B (64 k x 128 f)
      const int kb = t >> 2;          // 0..63
      const int cb = (t & 3) * 32;
      const float4* src = (const float4*)(W + (size_t)(k0 + kb) * FOUT + cb);
      float4* dst = (float4*)&Bs[kb][cb];
      #pragma unroll
      for (int q = 0; q < 8; q++) dst[q] = src[q];
    }
    __syncthreads();
    #pragma unroll 4
    for (int k = 0; k < 64; k++) {
      float2 av = *(const float2*)&As[k][r*2];
      float b[8];
      *(float4*)&b[0] = *(const float4*)&Bs[k][c*8];
      *(float4*)&b[4] = *(const float4*)&Bs[k][c*8+4];
      #pragma unroll
      for (int j = 0; j < 8; j++) {
        acc0[j] = fmaf(av.x, b[j], acc0[j]);
        acc1[j] = fmaf(av.y, b[j], acc1[j]);
      }
    }
    __syncthreads();
  }

  // epilogue: Cs tile + per-row dots with a1/a2
  float p1a = 0.f, p2a = 0.f, p1b = 0.f, p2b = 0.f;
  #pragma unroll
  for (int j = 0; j < 8; j++) {
    Cs[r*2][c*8+j]   = acc0[j];
    Cs[r*2+1][c*8+j] = acc1[j];
    float w1 = a[c*8+j];
    float w2 = a[FOUT + c*8+j];
    p1a = fmaf(acc0[j], w1, p1a); p2a = fmaf(acc0[j], w2, p2a);
    p1b = fmaf(acc1[j], w1, p1b); p2b = fmaf(acc1[j], w2, p2b);
  }
  red1[r*2][c]   = p1a; red2[r*2][c]   = p2a;
  red1[r*2+1][c] = p1b; red2[r*2+1][c] = p2b;
  __syncthreads();
  if (t < 32) {
    float s = 0.f;
    #pragma unroll
    for (int q = 0; q < 16; q++) s += red1[t][q];
    Wh1[i0 + t] = s;
  } else if (t < 64) {
    float s = 0.f;
    #pragma unroll
    for (int q = 0; q < 16; q++) s += red2[t-32][q];
    Wh2[i0 + t - 32] = s;
  }
  { // WhbT store: thread -> (f = t&127, i-halves of 16)
    const int f = t & 127, half = t >> 7;
    union { bf16_t b[16]; uint4 v[2]; } pk;
    #pragma unroll
    for (int q = 0; q < 16; q++) pk.b[q] = (bf16_t)Cs[half*16 + q][f];
    uint4* dst = (uint4*)(WhbT + (size_t)f * NV + i0 + half*16);
    dst[0] = pk.v[0]; dst[1] = pk.v[1];
  }
}

// ---------------------------------------------------------------------------
// Kernel 2: fused masked-softmax attention. adj is the irreducible 268 MB
// stream — restructured for streaming: 8 col-splits (grid 1024, >=3 blocks/CU),
// depth-1 register prefetch of the next adj chunk, and a pre-MFMA barrier that
// does NOT drain vmcnt so the prefetch stays in flight across it.
// ---------------------------------------------------------------------------
__global__ __launch_bounds__(256, 3) void attn_kernel(
    const int* __restrict__ adj, const bf16_t* __restrict__ WhbT,
    const float* __restrict__ Wh1v, const float* __restrict__ Wh2v,
    float* __restrict__ nump, float* __restrict__ denp)
{
  __shared__ bf16_t Plds[64][72];    // P tile, padded rows (144 B, 16B-aligned)
  __shared__ bf16_t Blds[128][72];   // Whb^T tile [f][k]
  __shared__ float denlds[64][4];
  const int t     = threadIdx.x;
  const int rb    = blockIdx.x >> 3;
  const int split = blockIdx.x & 7;
  const int i0 = rb * 64;
  const int j0 = split * SPLITW;
  const int il = t >> 2;            // 0..63: local row for P compute
  const int jg = (t & 3) * 16;      // 16-col strip within chunk
  const float wh1 = Wh1v[i0 + il];
  const int lane = t & 63;
  const int w    = t >> 6;
  const int rh = (w & 1) * 32;      // wave row offset
  const int ch = (w >> 1) * 64;     // wave col offset
  const int ml = lane & 31;
  const int kh = (lane >> 5) * 8;
  f32x16 acc0 = {};
  f32x16 acc1 = {};
  float den_t = 0.f;

  const int* arow = adj + (size_t)(i0 + il) * NV + j0 + jg;
  // prologue: prefetch chunk 0 into registers
  int4 ca0 = *(const int4*)(arow + 0);
  int4 ca1 = *(const int4*)(arow + 4);
  int4 ca2 = *(const int4*)(arow + 8);
  int4 ca3 = *(const int4*)(arow + 12);

  for (int jc = 0; jc < SPLITW; jc += 64) {
    const int jb = j0 + jc;
    // issue next chunk's adj loads FIRST (last iter re-reads current: L2 hit,
    // keeps the loop branchless). Consumed only after the next __syncthreads.
    const int jn = (jc + 64 < SPLITW) ? jc + 64 : jc;
    const int* nrow = arow + jn;
    int4 na0 = *(const int4*)(nrow + 0);
    int4 na1 = *(const int4*)(nrow + 4);
    int4 na2 = *(const int4*)(nrow + 8);
    int4 na3 = *(const int4*)(nrow + 12);
    { // stage B: Blds[f][k] = WhbT[f][jb+k]  (L2-resident, 16 KB)
      const int n  = t >> 1;
      const int hf = (t & 1) * 32;
      const uint4* s4 = (const uint4*)(WhbT + (size_t)n * NV + jb + hf);
      uint4* dst = (uint4*)&Blds[n][hf];
      dst[0] = s4[0]; dst[1] = s4[1]; dst[2] = s4[2]; dst[3] = s4[3];
    }
    { // compute P strip (1 row x 16 cols per thread) from current registers
      float4 w0 = *(const float4*)(Wh2v + jb + jg);
      float4 w1 = *(const float4*)(Wh2v + jb + jg + 4);
      float4 w2 = *(const float4*)(Wh2v + jb + jg + 8);
      float4 w3 = *(const float4*)(Wh2v + jb + jg + 12);
      const int am[16] = {ca0.x,ca0.y,ca0.z,ca0.w, ca1.x,ca1.y,ca1.z,ca1.w,
                          ca2.x,ca2.y,ca2.z,ca2.w, ca3.x,ca3.y,ca3.z,ca3.w};
      const float wm[16] = {w0.x,w0.y,w0.z,w0.w, w1.x,w1.y,w1.z,w1.w,
                            w2.x,w2.y,w2.z,w2.w, w3.x,w3.y,w3.z,w3.w};
      bf16x8 pv0, pv1;
      #pragma unroll
      for (int q = 0; q < 16; q++) {
        float e = wh1 + wm[q];
        e = fmaxf(e, 0.2f * e);                 // LeakyReLU(0.2)
        float p = (am[q] > 0) ? __expf(e) : 0.0f;
        den_t += p;
        if (q < 8) pv0[q] = (bf16_t)p; else pv1[q-8] = (bf16_t)p;
      }
      *(bf16x8*)&Plds[il][jg]     = pv0;
      *(bf16x8*)&Plds[il][jg + 8] = pv1;
    }
    // b1: order LDS writes + barrier WITHOUT the compiler's vmcnt(0) drain —
    // the adj prefetch stays in flight through the MFMA phase.
    asm volatile("s_waitcnt lgkmcnt(0)\n\ts_barrier" ::: "memory");
    // MFMA: wave computes 32 rows x 64 cols; K = 64 in 4 steps of 16
    #pragma unroll
    for (int ks = 0; ks < 4; ks++) {
      const int k = ks * 16 + kh;
      bf16x8 af = *(const bf16x8*)&Plds[rh + ml][k];
      bf16x8 b0 = *(const bf16x8*)&Blds[ch + ml][k];
      bf16x8 b1 = *(const bf16x8*)&Blds[ch + 32 + ml][k];
      acc0 = __builtin_amdgcn_mfma_f32_32x32x16_bf16(af, b0, acc0, 0, 0, 0);
      acc1 = __builtin_amdgcn_mfma_f32_32x32x16_bf16(af, b1, acc1, 0, 0, 0);
    }
    // b2: full barrier before Plds/Blds are overwritten next iteration
    // (drains vmcnt here — prefetch has had P-compute + b1 + MFMA to land).
    __syncthreads();
    ca0 = na0; ca1 = na1; ca2 = na2; ca3 = na3;
  }

  // epilogue: den reduce (4 partials per row)
  denlds[il][t & 3] = den_t;
  __syncthreads();
  if (t < 64) {
    denp[(size_t)split * NV + i0 + t] =
        denlds[t][0] + denlds[t][1] + denlds[t][2] + denlds[t][3];
  }
  // num partial write; C/D layout: col = lane&31, row = (reg&3)+8*(reg>>2)+4*(lane>>5)
  float* base = nump + ((size_t)split * NV + i0) * FOUT;
  const int col = ch + ml;
  const int r4  = 4 * (lane >> 5);
  #pragma unroll
  for (int reg = 0; reg < 16; reg++) {
    const int row = rh + (reg & 3) + 8 * (reg >> 2) + r4;
    base[(size_t)row * FOUT + col]      = acc0[reg];
    base[(size_t)row * FOUT + col + 32] = acc1[reg];
  }
}

// ---------------------------------------------------------------------------
// Kernel 3: out = elu( (sum_s num_s) / (sum_s den_s) ), 8 splits
// ---------------------------------------------------------------------------
__global__ __launch_bounds__(256) void finalize_kernel(
    const float* __restrict__ nump, const float* __restrict__ denp,
    float* __restrict__ out)
{
  const int gid = blockIdx.x * 256 + threadIdx.x;   // 0 .. 262143
  const int i  = gid >> 5;
  const int f0 = (gid & 31) * 4;
  float den = 0.f;
  #pragma unroll
  for (int sp = 0; sp < NSPLIT; sp++) den += denp[(size_t)sp * NV + i];
  float4 s = make_float4(0.f, 0.f, 0.f, 0.f);
  #pragma unroll
  for (int sp = 0; sp < NSPLIT; sp++) {
    float4 v = *(const float4*)&nump[((size_t)sp * NV + i) * FOUT + f0];
    s.x += v.x; s.y += v.y; s.z += v.z; s.w += v.w;
  }
  const float inv = 1.0f / den;
  float4 r;
  r.x = s.x * inv; r.y = s.y * inv; r.z = s.z * inv; r.w = s.w * inv;
  r.x = r.x > 0.f ? r.x : __expf(r.x) - 1.0f;
  r.y = r.y > 0.f ? r.y : __expf(r.y) - 1.0f;
  r.z = r.z > 0.f ? r.z : __expf(r.z) - 1.0f;
  r.w = r.w > 0.f ? r.w : __expf(r.w) - 1.0f;
  *(float4*)&out[(size_t)i * FOUT + f0] = r;
}

// ---------------------------------------------------------------------------
extern "C" void kernel_launch(void* const* d_in, const int* in_sizes, int n_in,
                              void* d_out, int out_size, void* d_ws, size_t ws_size,
                              hipStream_t stream) {
  const float* h  = (const float*)d_in[0];
  const int*  adj = (const int*)d_in[1];
  const float* W  = (const float*)d_in[2];
  const float* a  = (const float*)d_in[3];
  float* out = (float*)d_out;
  char* ws = (char*)d_ws;
  // workspace layout (~34.4 MB total):
  bf16_t* WhbT = (bf16_t*)ws;                                  // 2 MB
  float* Wh1  = (float*)(ws + 2097152);                        // 32 KB
  float* Wh2  = (float*)(ws + 2097152 + 32768);                // 32 KB
  float* denp = (float*)(ws + 2097152 + 65536);                // 256 KB (8 splits)
  float* nump = (float*)(ws + 2097152 + 65536 + 262144);       // 32 MB  (8 splits)

  wh_kernel<<<256, 256, 0, stream>>>(h, W, a, WhbT, Wh1, Wh2);
  attn_kernel<<<1024, 256, 0, stream>>>(adj, WhbT, Wh1, Wh2, nump, denp);
  finalize_kernel<<<1024, 256, 0, stream>>>(nump, denp, out);
}